// Round 24
// baseline (957.873 us; speedup 1.0000x reference)
//
#include <hip/hip_runtime.h>
#include <math.h>

#define BTOT   32768
#define LAT    128
#define H      17
#define G4     68
#define TSTEPS 50
#define NPR    102     // 68 (W_ih) + 17 (W_h0) + 17 (W_c0)
#define WPAD   40
#define XPAD   132
#define ROWS   64      // rows per block = lanes per wave
#define TPB    1024    // 16 waves; wave jw owns element jw (0..15); j=16 split
#define OSTR   (TSTEPS * H)   // 850

#define XSWZ(r, c4)   ((c4) ^ ((((r) >> 3) & 3) << 2))
#define WSWZ(row, c4) ((c4) ^ ((((row) >> 2) & 3) << 2))

// f32-only gates (R9: recurrence amplifies per-step error ~1e3x; f16 fails).
__device__ __forceinline__ float fsigmoid(float x) {
    float e = __expf(-x);
    return __builtin_amdgcn_rcpf(1.0f + e);
}
__device__ __forceinline__ float ftanhf(float x) {
    float e = __expf(2.0f * x);
    float t = __builtin_amdgcn_rcpf(e + 1.0f);
    return fmaf(-2.0f, t, 1.0f);
}

// wave = j-element (W_hh slice wave-uniform -> 68 SGPRs, v_fmac v,s,v, ZERO
// copies -- the AGPR copy tax that floored R6..R23 at ~131us is structurally
// eliminated). lane = row (64/64 lanes active). 512 blocks = 2/CU co-resident.
__global__ __launch_bounds__(TPB, 8)
void lstm_sgpr(const float* __restrict__ x,
               const float* __restrict__ W_h0, const float* __restrict__ b_h0,
               const float* __restrict__ W_c0, const float* __restrict__ b_c0,
               const float* __restrict__ W_ih, const float* __restrict__ W_hh,
               const float* __restrict__ b_ih, const float* __restrict__ b_hh,
               float* __restrict__ out)
{
    __shared__ __align__(16) float x_tile[ROWS][XPAD];   // 33.8 KB
    __shared__ __align__(16) float Wbuf[NPR][WPAD];      // 16.3 KB (k-quarter)
    __shared__ __align__(16) float hbufs[2][H][ROWS];    //  8.7 KB (transposed)
    __shared__ __align__(16) float pbuf[4][4][ROWS];     //  4.1 KB (j16 partials)
    // 62.9 KB -> exactly 2 blocks/CU; grid 512 = 2 x 256, fully co-resident.

    const int t    = threadIdx.x;
    const int lane = t & 63;                                  // row
    const int jw   = __builtin_amdgcn_readfirstlane(t >> 6);  // wave's j (0..15)
    const bool w4  = (jw == 4);                               // also owns j=16 tail
    const int grow0 = blockIdx.x * ROWS;

    // ---- stage x tile ----
    for (int i = t; i < ROWS * 32; i += TPB) {
        int rr = i >> 5, c4 = (i & 31) * 4;
        *(float4*)&x_tile[rr][XSWZ(rr, c4)] =
            *(const float4*)(x + (size_t)(grow0 + rr) * LAT + c4);
    }

    // ---- phase 1: 6 dots for (row=lane, j=jw); wave 4 also j=16 ----
    float acc[6]  = {0.f, 0.f, 0.f, 0.f, 0.f, 0.f};
    float accB[6] = {0.f, 0.f, 0.f, 0.f, 0.f, 0.f};
    for (int qh = 0; qh < 4; ++qh) {
        __syncthreads();  // qh=0: x_tile ready; else WAR on Wbuf
        for (int i = t; i < NPR * 8; i += TPB) {
            int row = i >> 3, c4 = (i & 7) * 4;
            const float* src = (row < G4) ? (W_ih + row * LAT)
                             : (row < 85) ? (W_h0 + (row - G4) * LAT)
                                          : (W_c0 + (row - 85) * LAT);
            *(float4*)&Wbuf[row][WSWZ(row, c4)] = *(const float4*)(src + qh * 32 + c4);
        }
        __syncthreads();
        for (int kb = 0; kb < 8; ++kb) {
            const int xc = qh * 32 + kb * 4;
            float4 xv = *(const float4*)&x_tile[lane][XSWZ(lane, xc)];
#pragma unroll
            for (int p = 0; p < 6; ++p) {
                const int row = (p < 4) ? (p * H + jw) : ((p == 4) ? (G4 + jw) : (85 + jw));
                float4 wv = *(const float4*)&Wbuf[row][WSWZ(row, kb * 4)];  // uniform -> bcast
                acc[p] = fmaf(xv.x, wv.x, acc[p]);
                acc[p] = fmaf(xv.y, wv.y, acc[p]);
                acc[p] = fmaf(xv.z, wv.z, acc[p]);
                acc[p] = fmaf(xv.w, wv.w, acc[p]);
            }
            if (w4) {
#pragma unroll
                for (int p = 0; p < 6; ++p) {
                    const int row = (p < 4) ? (p * H + 16) : ((p == 4) ? (G4 + 16) : (85 + 16));
                    float4 wv = *(const float4*)&Wbuf[row][WSWZ(row, kb * 4)];
                    accB[p] = fmaf(xv.x, wv.x, accB[p]);
                    accB[p] = fmaf(xv.y, wv.y, accB[p]);
                    accB[p] = fmaf(xv.z, wv.z, accB[p]);
                    accB[p] = fmaf(xv.w, wv.w, accB[p]);
                }
            }
        }
    }

    // biases (uniform scalars)
    const float xg0 = acc[0] + b_ih[0 * H + jw] + b_hh[0 * H + jw];
    const float xg1 = acc[1] + b_ih[1 * H + jw] + b_hh[1 * H + jw];
    const float xg2 = acc[2] + b_ih[2 * H + jw] + b_hh[2 * H + jw];
    const float xg3 = acc[3] + b_ih[3 * H + jw] + b_hh[3 * H + jw];
    float c = acc[5] + b_c0[jw];
    const float h0own = acc[4] + b_h0[jw];
    float xB0 = 0.f, xB1 = 0.f, xB2 = 0.f, xB3 = 0.f, c16 = 0.f, h0B = 0.f;
    if (w4) {
        xB0 = accB[0] + b_ih[0 * H + 16] + b_hh[0 * H + 16];
        xB1 = accB[1] + b_ih[1 * H + 16] + b_hh[1 * H + 16];
        xB2 = accB[2] + b_ih[2 * H + 16] + b_hh[2 * H + 16];
        xB3 = accB[3] + b_ih[3 * H + 16] + b_hh[3 * H + 16];
        c16 = accB[5] + b_c0[16];
        h0B = accB[4] + b_h0[16];
    }

    // ---- W_hh slice for this wave's j: 68 wave-uniform values -> SGPRs ----
    float Ws0[H], Ws1[H], Ws2[H], Ws3[H];
#pragma unroll
    for (int k = 0; k < H; ++k) {
        Ws0[k] = W_hh[(0 * H + jw) * H + k];
        Ws1[k] = W_hh[(1 * H + jw) * H + k];
        Ws2[k] = W_hh[(2 * H + jw) * H + k];
        Ws3[k] = W_hh[(3 * H + jw) * H + k];
    }
    // j16 partial-W (waves 0-3; uniform): wave w covers k = 4w..4w+3 (+k16 on w3)
    float Wp0[4], Wp1[4], Wp2[4], Wp3[4];
    float Wq0 = 0.f, Wq1 = 0.f, Wq2 = 0.f, Wq3 = 0.f;
    if (jw < 4) {
#pragma unroll
        for (int m = 0; m < 4; ++m) {
            Wp0[m] = W_hh[(0 * H + 16) * H + jw * 4 + m];
            Wp1[m] = W_hh[(1 * H + 16) * H + jw * 4 + m];
            Wp2[m] = W_hh[(2 * H + 16) * H + jw * 4 + m];
            Wp3[m] = W_hh[(3 * H + 16) * H + jw * 4 + m];
        }
        if (jw == 3) {
            Wq0 = W_hh[(0 * H + 16) * H + 16];
            Wq1 = W_hh[(1 * H + 16) * H + 16];
            Wq2 = W_hh[(2 * H + 16) * H + 16];
            Wq3 = W_hh[(3 * H + 16) * H + 16];
        }
    }

    // ---- publish h0 ----
    float* hrd = &hbufs[0][0][0];
    float* hwr = &hbufs[1][0][0];
    hrd[jw * ROWS + lane] = h0own;
    if (w4) hrd[16 * ROWS + lane] = h0B;

    // coalesced out-copy assignment (LDS bounce): thread t owns flat elem t (+1024)
    const int rr1 = t / H, jj1 = t - rr1 * H;
    float* o1 = out + (size_t)(grow0 + rr1) * OSTR + jj1;
    const bool has2 = (t < ROWS * H - TPB);   // 64 threads carry a 2nd element
    const int e2 = TPB + t;
    const int rr2 = e2 / H, jj2 = e2 - rr2 * H;
    float* o2 = out + (size_t)(grow0 + rr2) * OSTR + jj2;

    __syncthreads();   // h0 visible

    // ---- T-loop: 2 barriers/step ----
    for (int tt = 0; tt < TSTEPS; ++tt) {
        float hk[H];
#pragma unroll
        for (int k = 0; k < H; ++k) hk[k] = hrd[k * ROWS + lane];  // consec-lane: free

        float ai = xg0, af = xg1, ag = xg2, ao = xg3;
#pragma unroll
        for (int k = 0; k < H; ++k) {
            ai = fmaf(Ws0[k], hk[k], ai);   // v_fmac v, s, v  -- no copies
            af = fmaf(Ws1[k], hk[k], af);
            ag = fmaf(Ws2[k], hk[k], ag);
            ao = fmaf(Ws3[k], hk[k], ao);
        }
        const float ig = fsigmoid(ai), fg = fsigmoid(af);
        const float gv = ftanhf(ag),  og = fsigmoid(ao);
        c = fmaf(fg, c, ig * gv);
        const float hnew = og * ftanhf(c);
        hwr[jw * ROWS + lane] = hnew;

        if (jw < 4) {   // j16 partial dots (k-split, LDS re-read avoids dyn idx)
            float q0 = 0.f, q1 = 0.f, q2 = 0.f, q3 = 0.f;
#pragma unroll
            for (int m = 0; m < 4; ++m) {
                float hh = hrd[(jw * 4 + m) * ROWS + lane];
                q0 = fmaf(Wp0[m], hh, q0);
                q1 = fmaf(Wp1[m], hh, q1);
                q2 = fmaf(Wp2[m], hh, q2);
                q3 = fmaf(Wp3[m], hh, q3);
            }
            if (jw == 3) {
                q0 = fmaf(Wq0, hk[16], q0);
                q1 = fmaf(Wq1, hk[16], q1);
                q2 = fmaf(Wq2, hk[16], q2);
                q3 = fmaf(Wq3, hk[16], q3);
            }
            pbuf[jw][0][lane] = q0; pbuf[jw][1][lane] = q1;
            pbuf[jw][2][lane] = q2; pbuf[jw][3][lane] = q3;
        }
        __syncthreads();   // A: own-j h writes + partials complete

        if (w4) {          // j16 tail (state lives in wave 4's threads)
            float s0 = xB0 + pbuf[0][0][lane] + pbuf[1][0][lane] + pbuf[2][0][lane] + pbuf[3][0][lane];
            float s1 = xB1 + pbuf[0][1][lane] + pbuf[1][1][lane] + pbuf[2][1][lane] + pbuf[3][1][lane];
            float s2 = xB2 + pbuf[0][2][lane] + pbuf[1][2][lane] + pbuf[2][2][lane] + pbuf[3][2][lane];
            float s3 = xB3 + pbuf[0][3][lane] + pbuf[1][3][lane] + pbuf[2][3][lane] + pbuf[3][3][lane];
            const float ig2 = fsigmoid(s0), fg2 = fsigmoid(s1);
            const float gv2 = ftanhf(s2),  og2 = fsigmoid(s3);
            c16 = fmaf(fg2, c16, ig2 * gv2);
            hwr[16 * ROWS + lane] = og2 * ftanhf(c16);
        }
        __syncthreads();   // B: hwr fully complete (incl j16)

        // coalesced out copy of h_{tt+1}
        o1[0] = hwr[jj1 * ROWS + rr1]; o1 += H;
        if (has2) { o2[0] = hwr[jj2 * ROWS + rr2]; o2 += H; }

        float* tmp = hrd; hrd = hwr; hwr = tmp;
    }
}

extern "C" void kernel_launch(void* const* d_in, const int* in_sizes, int n_in,
                              void* d_out, int out_size, void* d_ws, size_t ws_size,
                              hipStream_t stream)
{
    const float* x    = (const float*)d_in[0];
    const float* W_h0 = (const float*)d_in[1];
    const float* b_h0 = (const float*)d_in[2];
    const float* W_c0 = (const float*)d_in[3];
    const float* b_c0 = (const float*)d_in[4];
    const float* W_ih = (const float*)d_in[5];
    const float* W_hh = (const float*)d_in[6];
    const float* b_ih = (const float*)d_in[7];
    const float* b_hh = (const float*)d_in[8];
    float* out = (float*)d_out;

    (void)d_ws; (void)ws_size;  // no workspace used

    hipLaunchKernelGGL(lstm_sgpr, dim3(BTOT / ROWS), dim3(TPB), 0, stream,
                       x, W_h0, b_h0, W_c0, b_c0, W_ih, W_hh, b_ih, b_hh, out);
}

// Round 25
// 183.333 us; speedup vs baseline: 5.2248x; 5.2248x over previous
//
#include <hip/hip_runtime.h>
#include <math.h>

#define BTOT   32768
#define LAT    128
#define H      17
#define G4     68      // 4*H
#define TSTEPS 50
#define NPR    102     // projection rows: 68 (W_ih) + 17 (W_h0) + 17 (W_c0)
#define WPAD   40      // Wbuf row stride (k-quarter staging, R14-proven)
#define XPAD   132

#define NW     4              // waves per block (small blocks -> decorrelated)
#define RPB    12             // 3 rows per wave, 51/64 lanes active
#define TPB    256

// x_tile stride 132: rows r,r+8 alias -> 2-bit XOR key (R13/R14-proven).
#define XSWZ(r, c4)   ((c4) ^ ((((r) >> 3) & 3) << 2))
// Wbuf stride 40: rows r,r+4 alias -> key on bits 2-3 (R14-proven).
#define WSWZ(row, c4) ((c4) ^ ((((row) >> 2) & 3) << 2))

// f32-only gates (R9: recurrence amplifies per-step error ~1e3x; f16 fails).
__device__ __forceinline__ float fsigmoid(float x) {
    float e = __expf(-x);
    return __builtin_amdgcn_rcpf(1.0f + e);
}
// tanh(x) = 1 - 2*rcp(exp(2x)+1); +inf -> 1, -inf -> -1, no divide.
__device__ __forceinline__ float ftanhf(float x) {
    float e = __expf(2.0f * x);
    float t = __builtin_amdgcn_rcpf(e + 1.0f);
    return fmaf(-2.0f, t, 1.0f);
}

// R21 finding: gfx950 VALU cannot source AGPRs -> keep "v" constraint.
#define FMAC(acc, w, h) asm("v_fmac_f32 %0, %1, %2" : "+v"(acc) : "v"(w), "v"(h))

#define FK(K) \
    FMAC(ai, Wi[K], hk[K]); FMAC(af, Wf[K], hk[K]); \
    FMAC(ag, Wg[K], hk[K]); FMAC(ao, Wo[K], hk[K]);

// (256,4): unified reg cap 128; R20-proven structure (45% occupancy, best 131us).
// R25 change: h-exchange via __shfl (ds_bpermute on registers) -- the LDS
// write->wait->read round-trip (~100+ exposed cycles in every step's serial
// chain since R6) is deleted; T-loop touches no LDS storage, zero barriers.
__global__ __launch_bounds__(TPB, 4)
void lstm_fused(const float* __restrict__ x,
                const float* __restrict__ W_h0, const float* __restrict__ b_h0,
                const float* __restrict__ W_c0, const float* __restrict__ b_c0,
                const float* __restrict__ W_ih, const float* __restrict__ W_hh,
                const float* __restrict__ b_ih, const float* __restrict__ b_hh,
                float* __restrict__ out)
{
    __shared__ __align__(16) float x_tile[RPB][XPAD];   //  6.3 KB
    __shared__ __align__(16) float Wbuf[NPR][WPAD];     // 16.3 KB (one k-quarter)
    __shared__ __align__(16) float Wl[G4 * H];          //  4.6 KB (W_hh f32)
    // total 27.2 KB; occupancy reg-capped at 4 blocks/CU (R20: 45%).

    const int t    = threadIdx.x;
    const int lane = t & 63;
    const bool active = lane < 3 * H;         // 51
    const int rl = active ? (lane / H) : 0;   // 0..2
    const int j  = active ? (lane % H) : 0;   // 0..16
    const int rbase = rl * H;                 // wave-local source-lane base
    const int w    = t >> 6;
    const int r0 = w * 3 + rl;                // block-local row 0..11
    const int grow0 = blockIdx.x * RPB;
    int grow = grow0 + r0;
    const bool valid = active && (grow < BTOT);
    if (grow >= BTOT) grow = BTOT - 1;

    // ---- stage x tile (rows clamped) + W_hh; all 256 threads ----
    for (int i = t; i < RPB * 32; i += TPB) {              // 384 float4
        int rr = i >> 5, c4 = (i & 31) * 4;
        int gr = grow0 + rr; if (gr >= BTOT) gr = BTOT - 1;
        *(float4*)&x_tile[rr][XSWZ(rr, c4)] = *(const float4*)(x + (size_t)gr * LAT + c4);
    }
    for (int i = t; i < G4 * H; i += TPB) Wl[i] = W_hh[i];

    // ---- phase 1: projections, four k-quarters of 32 (R14-proven layout) ----
    float acc[6] = {0.f, 0.f, 0.f, 0.f, 0.f, 0.f};         // i,f,g,o, h0, c0
    const int rows6[6] = { j, 17 + j, 34 + j, 51 + j, 68 + j, 85 + j };
    for (int qh = 0; qh < 4; ++qh) {
        __syncthreads();  // qh=0: x_tile/Wl ready; else WAR on Wbuf
        for (int i = t; i < NPR * 8; i += TPB) {           // 8 float4 per quarter-row
            int row = i >> 3, c4 = (i & 7) * 4;
            const float* src = (row < G4) ? (W_ih + row * LAT)
                             : (row < 85) ? (W_h0 + (row - G4) * LAT)
                                          : (W_c0 + (row - 85) * LAT);
            *(float4*)&Wbuf[row][WSWZ(row, c4)] = *(const float4*)(src + qh * 32 + c4);
        }
        __syncthreads();  // quarter ready
        for (int kb = 0; kb < 8; ++kb) {
            const int xc = qh * 32 + kb * 4;
            float4 xv = *(const float4*)&x_tile[r0][XSWZ(r0, xc)];
#pragma unroll
            for (int p = 0; p < 6; ++p) {
                const int row = rows6[p];
                float4 wv = *(const float4*)&Wbuf[row][WSWZ(row, kb * 4)];
                acc[p] = fmaf(xv.x, wv.x, acc[p]);
                acc[p] = fmaf(xv.y, wv.y, acc[p]);
                acc[p] = fmaf(xv.z, wv.z, acc[p]);
                acc[p] = fmaf(xv.w, wv.w, acc[p]);
            }
        }
    }

    const float xgi = acc[0] + b_ih[j]      + b_hh[j];
    const float xgf = acc[1] + b_ih[17 + j] + b_hh[17 + j];
    const float xgg = acc[2] + b_ih[34 + j] + b_hh[34 + j];
    const float xgo = acc[3] + b_ih[51 + j] + b_hh[51 + j];
    float h = acc[4] + b_h0[j];
    float c = acc[5] + b_c0[j];

    // ---- W_hh rows for gates i,f,g,o of element j -> registers ----
    float Wi[H], Wf[H], Wg[H], Wo[H];
#pragma unroll
    for (int k = 0; k < H; ++k) {
        Wi[k] = Wl[(0 * H + j) * H + k];
        Wf[k] = Wl[(1 * H + j) * H + k];
        Wg[k] = Wl[(2 * H + j) * H + k];
        Wo[k] = Wl[(3 * H + j) * H + k];
        asm volatile("" : "+v"(Wi[k]), "+v"(Wf[k]), "+v"(Wg[k]), "+v"(Wo[k]));
    }

    // ---- phase 2: recurrence with REGISTER exchange (shfl/bpermute) ----
    // No LDS storage, no write->read wait, no barriers in the T-loop.
    float* orow = out + (size_t)grow * (TSTEPS * H) + j;

    for (int tt = 0; tt < TSTEPS; ++tt) {
        float hk[H];
#pragma unroll
        for (int k = 0; k < H; ++k) hk[k] = __shfl(h, rbase + k, 64);

        float ai = xgi, af = xgf, ag = xgg, ao = xgo;
        FK(0)  FK(1)  FK(2)  FK(3)  FK(4)  FK(5)  FK(6)  FK(7)
        FK(8)  FK(9)  FK(10) FK(11) FK(12) FK(13) FK(14) FK(15) FK(16)

        const float ig = fsigmoid(ai), fg = fsigmoid(af);
        const float gv = ftanhf(ag),  og = fsigmoid(ao);
        c = fmaf(fg, c, ig * gv);
        h = og * ftanhf(c);

        if (valid) orow[tt * H] = h;
    }
}

extern "C" void kernel_launch(void* const* d_in, const int* in_sizes, int n_in,
                              void* d_out, int out_size, void* d_ws, size_t ws_size,
                              hipStream_t stream)
{
    const float* x    = (const float*)d_in[0];
    const float* W_h0 = (const float*)d_in[1];
    const float* b_h0 = (const float*)d_in[2];
    const float* W_c0 = (const float*)d_in[3];
    const float* b_c0 = (const float*)d_in[4];
    const float* W_ih = (const float*)d_in[5];
    const float* W_hh = (const float*)d_in[6];
    const float* b_ih = (const float*)d_in[7];
    const float* b_hh = (const float*)d_in[8];
    float* out = (float*)d_out;

    (void)d_ws; (void)ws_size;  // no workspace used

    const int nblk = (BTOT + RPB - 1) / RPB;   // 2731
    hipLaunchKernelGGL(lstm_fused, dim3(nblk), dim3(TPB), 0, stream,
                       x, W_h0, b_h0, W_c0, b_c0, W_ih, W_hh, b_ih, b_hh, out);
}

// Round 26
// 134.907 us; speedup vs baseline: 7.1002x; 1.3590x over previous
//
#include <hip/hip_runtime.h>
#include <math.h>

#define BTOT   32768
#define LAT    128
#define H      17
#define G4     68      // 4*H
#define TSTEPS 50
#define NPR    102     // projection rows: 68 (W_ih) + 17 (W_h0) + 17 (W_c0)
#define WPAD   40      // Wbuf row stride (k-quarter staging, R14-proven)
#define XPAD   132

#define NW     4              // waves per block (R20-proven small-block shape)
#define RPB    24             // 6 rows per wave: set A rl, set B rl+3; 51 lanes
#define TPB    256

// x_tile stride 132: rows r,r+8 alias -> 2-bit XOR key (R13/R14-proven).
#define XSWZ(r, c4)   ((c4) ^ ((((r) >> 3) & 3) << 2))
// Wbuf stride 40: rows r,r+4 alias -> key on bits 2-3 (R14-proven).
#define WSWZ(row, c4) ((c4) ^ ((((row) >> 2) & 3) << 2))

// f32-only gates (R9: recurrence amplifies per-step error ~1e3x; f16 fails).
__device__ __forceinline__ float fsigmoid(float x) {
    float e = __expf(-x);
    return __builtin_amdgcn_rcpf(1.0f + e);
}
// tanh(x) = 1 - 2*rcp(exp(2x)+1); +inf -> 1, -inf -> -1, no divide.
__device__ __forceinline__ float ftanhf(float x) {
    float e = __expf(2.0f * x);
    float t = __builtin_amdgcn_rcpf(e + 1.0f);
    return fmaf(-2.0f, t, 1.0f);
}

// R21 finding: gfx950 VALU cannot source AGPRs -> "v" constraint; the
// v_accvgpr_read copies are unavoidable, but here each copy feeds TWO sets'
// FMAs (A and B share W) -> copy tax per set halves vs R20.
#define FMAC(acc, w, h) asm("v_fmac_f32 %0, %1, %2" : "+v"(acc) : "v"(w), "v"(h))

#define FQ(Q, HV) \
    FMAC(ai,Wi[4*Q+0],HV.x); FMAC(af,Wf[4*Q+0],HV.x); FMAC(ag,Wg[4*Q+0],HV.x); FMAC(ao,Wo[4*Q+0],HV.x); \
    FMAC(ai,Wi[4*Q+1],HV.y); FMAC(af,Wf[4*Q+1],HV.y); FMAC(ag,Wg[4*Q+1],HV.y); FMAC(ao,Wo[4*Q+1],HV.y); \
    FMAC(ai,Wi[4*Q+2],HV.z); FMAC(af,Wf[4*Q+2],HV.z); FMAC(ag,Wg[4*Q+2],HV.z); FMAC(ao,Wo[4*Q+2],HV.z); \
    FMAC(ai,Wi[4*Q+3],HV.w); FMAC(af,Wf[4*Q+3],HV.w); FMAC(ag,Wg[4*Q+3],HV.w); FMAC(ao,Wo[4*Q+3],HV.w);

// (256,4): unified reg cap 128 (R20-proven no-spill); LDS 35.8KB -> 4 blocks/CU.
__global__ __launch_bounds__(TPB, 4)
void lstm_fused(const float* __restrict__ x,
                const float* __restrict__ W_h0, const float* __restrict__ b_h0,
                const float* __restrict__ W_c0, const float* __restrict__ b_c0,
                const float* __restrict__ W_ih, const float* __restrict__ W_hh,
                const float* __restrict__ b_ih, const float* __restrict__ b_hh,
                float* __restrict__ out)
{
    __shared__ __align__(16) float x_tile[RPB][XPAD];   // 12.7 KB
    __shared__ __align__(16) float Wbuf[NPR][WPAD];     // 16.3 KB (one k-quarter)
    __shared__ __align__(16) float Wl[G4 * H];          //  4.6 KB (W_hh f32)
    __shared__ __align__(16) float hbuf[NW][6][20];     //  1.9 KB
    // total 35.8 KB -> 4 blocks/CU; grid 1366.

    const int t    = threadIdx.x;
    const int w    = t >> 6;
    const int lane = t & 63;
    const bool active = lane < 3 * H;         // 51
    const int rl = active ? (lane / H) : 0;   // 0..2
    const int j  = active ? (lane % H) : 0;   // 0..16
    const int rA = w * 6 + rl;                // set-A block-local row
    const int rB = rA + 3;                    // set-B block-local row
    const int grow0 = blockIdx.x * RPB;
    int gA = grow0 + rA, gB = grow0 + rB;
    const bool vA = active && (gA < BTOT), vB = active && (gB < BTOT);
    if (gA >= BTOT) gA = BTOT - 1;
    if (gB >= BTOT) gB = BTOT - 1;

    // ---- stage x tile (rows clamped) + W_hh; all 256 threads ----
    for (int i = t; i < RPB * 32; i += TPB) {              // 768 float4
        int rr = i >> 5, c4 = (i & 31) * 4;
        int gr = grow0 + rr; if (gr >= BTOT) gr = BTOT - 1;
        *(float4*)&x_tile[rr][XSWZ(rr, c4)] = *(const float4*)(x + (size_t)gr * LAT + c4);
    }
    for (int i = t; i < G4 * H; i += TPB) Wl[i] = W_hh[i];

    // ---- phase 1: projections for both sets, four k-quarters of 32 ----
    float acc[12];                                         // A: 0-5, B: 6-11
#pragma unroll
    for (int s = 0; s < 12; ++s) acc[s] = 0.0f;
    const int rows6[6] = { j, 17 + j, 34 + j, 51 + j, 68 + j, 85 + j };
    for (int qh = 0; qh < 4; ++qh) {
        __syncthreads();  // qh=0: x_tile/Wl ready; else WAR on Wbuf
        for (int i = t; i < NPR * 8; i += TPB) {           // 8 float4 per quarter-row
            int row = i >> 3, c4 = (i & 7) * 4;
            const float* src = (row < G4) ? (W_ih + row * LAT)
                             : (row < 85) ? (W_h0 + (row - G4) * LAT)
                                          : (W_c0 + (row - 85) * LAT);
            *(float4*)&Wbuf[row][WSWZ(row, c4)] = *(const float4*)(src + qh * 32 + c4);
        }
        __syncthreads();  // quarter ready
        for (int kb = 0; kb < 8; ++kb) {
            const int xc = qh * 32 + kb * 4;
            float4 xa = *(const float4*)&x_tile[rA][XSWZ(rA, xc)];
            float4 xb = *(const float4*)&x_tile[rB][XSWZ(rB, xc)];
#pragma unroll
            for (int p = 0; p < 6; ++p) {
                const int row = rows6[p];
                float4 wv = *(const float4*)&Wbuf[row][WSWZ(row, kb * 4)];
                acc[p]     = fmaf(xa.x, wv.x, acc[p]);
                acc[p]     = fmaf(xa.y, wv.y, acc[p]);
                acc[p]     = fmaf(xa.z, wv.z, acc[p]);
                acc[p]     = fmaf(xa.w, wv.w, acc[p]);
                acc[6 + p] = fmaf(xb.x, wv.x, acc[6 + p]);
                acc[6 + p] = fmaf(xb.y, wv.y, acc[6 + p]);
                acc[6 + p] = fmaf(xb.z, wv.z, acc[6 + p]);
                acc[6 + p] = fmaf(xb.w, wv.w, acc[6 + p]);
            }
        }
    }

    const float bi0 = b_ih[j]      + b_hh[j];
    const float bi1 = b_ih[17 + j] + b_hh[17 + j];
    const float bi2 = b_ih[34 + j] + b_hh[34 + j];
    const float bi3 = b_ih[51 + j] + b_hh[51 + j];
    const float xgAi = acc[0] + bi0, xgAf = acc[1] + bi1;
    const float xgAg = acc[2] + bi2, xgAo = acc[3] + bi3;
    const float xgBi = acc[6] + bi0, xgBf = acc[7] + bi1;
    const float xgBg = acc[8] + bi2, xgBo = acc[9] + bi3;
    float hA = acc[4]  + b_h0[j], cA = acc[5]  + b_c0[j];
    float hB = acc[10] + b_h0[j], cB = acc[11] + b_c0[j];

    // ---- W_hh rows for gates i,f,g,o of element j -> registers (shared A/B) ----
    float Wi[H], Wf[H], Wg[H], Wo[H];
#pragma unroll
    for (int k = 0; k < H; ++k) {
        Wi[k] = Wl[(0 * H + j) * H + k];
        Wf[k] = Wl[(1 * H + j) * H + k];
        Wg[k] = Wl[(2 * H + j) * H + k];
        Wo[k] = Wl[(3 * H + j) * H + k];
        asm volatile("" : "+v"(Wi[k]), "+v"(Wf[k]), "+v"(Wg[k]), "+v"(Wo[k]));
    }

    // ---- phase 2: R13 depth-2 A/B pipeline in R20's occupancy regime ----
    float* orowA = out + (size_t)gA * (TSTEPS * H) + j;
    float* orowB = out + (size_t)gB * (TSTEPS * H) + j;
    const float* hbA = &hbuf[w][rl][0];
    const float* hbB = &hbuf[w][3 + rl][0];

    // prologue: A's step-0 exchange
    if (active) hbuf[w][rl][j] = hA;
    float4 a0 = *(const float4*)&hbA[0];
    float4 a1 = *(const float4*)&hbA[4];
    float4 a2 = *(const float4*)&hbA[8];
    float4 a3 = *(const float4*)&hbA[12];
    float  a4 = hbA[16];

    for (int tt = 0; tt < TSTEPS; ++tt) {
        // --- B exchange for this step (consumed after A's compute) ---
        if (active) hbuf[w][3 + rl][j] = hB;
        float4 b0 = *(const float4*)&hbB[0];
        float4 b1 = *(const float4*)&hbB[4];
        float4 b2 = *(const float4*)&hbB[8];
        float4 b3 = *(const float4*)&hbB[12];
        float  b4 = hbB[16];

        // --- A compute ---
        {
            float ai = xgAi, af = xgAf, ag = xgAg, ao = xgAo;
            FQ(0, a0) FQ(1, a1) FQ(2, a2) FQ(3, a3)
            FMAC(ai, Wi[16], a4); FMAC(af, Wf[16], a4);
            FMAC(ag, Wg[16], a4); FMAC(ao, Wo[16], a4);
            const float ig = fsigmoid(ai), fg = fsigmoid(af);
            const float gv = ftanhf(ag),  og = fsigmoid(ao);
            cA = fmaf(fg, cA, ig * gv);
            hA = og * ftanhf(cA);
        }

        // --- A exchange for NEXT step (hidden under B's compute) ---
        if (active) hbuf[w][rl][j] = hA;
        a0 = *(const float4*)&hbA[0];
        a1 = *(const float4*)&hbA[4];
        a2 = *(const float4*)&hbA[8];
        a3 = *(const float4*)&hbA[12];
        a4 = hbA[16];

        // --- B compute ---
        {
            float ai = xgBi, af = xgBf, ag = xgBg, ao = xgBo;
            FQ(0, b0) FQ(1, b1) FQ(2, b2) FQ(3, b3)
            FMAC(ai, Wi[16], b4); FMAC(af, Wf[16], b4);
            FMAC(ag, Wg[16], b4); FMAC(ao, Wo[16], b4);
            const float ig = fsigmoid(ai), fg = fsigmoid(af);
            const float gv = ftanhf(ag),  og = fsigmoid(ao);
            cB = fmaf(fg, cB, ig * gv);
            hB = og * ftanhf(cB);
        }

        // --- stores (async vmem, off the critical path) ---
        if (vA) orowA[tt * H] = hA;
        if (vB) orowB[tt * H] = hB;
    }
}

extern "C" void kernel_launch(void* const* d_in, const int* in_sizes, int n_in,
                              void* d_out, int out_size, void* d_ws, size_t ws_size,
                              hipStream_t stream)
{
    const float* x    = (const float*)d_in[0];
    const float* W_h0 = (const float*)d_in[1];
    const float* b_h0 = (const float*)d_in[2];
    const float* W_c0 = (const float*)d_in[3];
    const float* b_c0 = (const float*)d_in[4];
    const float* W_ih = (const float*)d_in[5];
    const float* W_hh = (const float*)d_in[6];
    const float* b_ih = (const float*)d_in[7];
    const float* b_hh = (const float*)d_in[8];
    float* out = (float*)d_out;

    (void)d_ws; (void)ws_size;  // no workspace used

    const int nblk = (BTOT + RPB - 1) / RPB;   // 1366
    hipLaunchKernelGGL(lstm_fused, dim3(nblk), dim3(TPB), 0, stream,
                       x, W_h0, b_h0, W_c0, b_c0, W_ih, W_hh, b_ih, b_hh, out);
}